// Round 2
// baseline (115.208 us; speedup 1.0000x reference)
//
#include <hip/hip_runtime.h>

typedef float f32x4 __attribute__((ext_vector_type(4)));
typedef __bf16 bf16x8 __attribute__((ext_vector_type(8)));
typedef unsigned short u16x4 __attribute__((ext_vector_type(4)));

constexpr int V = 4096;

__device__ __forceinline__ unsigned short f2bf(float f) {
    unsigned int u = __float_as_uint(f);
    u += 0x7FFFu + ((u >> 16) & 1u);           // round-to-nearest-even
    return (unsigned short)(u >> 16);
}

// ---- kernel 1: z = W @ xv + b  -> bf16 (384 x 4096) --------------------
// grid (48 row-groups, 4 v-blocks), 256 thr. Each thread owns 4 v's.
__global__ __launch_bounds__(256) void k_z(const float* __restrict__ x,
                                           const float* __restrict__ W,
                                           const float* __restrict__ b,
                                           unsigned short* __restrict__ zb) {
    __shared__ float Ws[8 * 128];
    __shared__ float bs[8];
    const int rg = blockIdx.x;
    const int vb = blockIdx.y;
    const int t  = threadIdx.x;
    reinterpret_cast<f32x4*>(Ws)[t] = reinterpret_cast<const f32x4*>(W + rg * 1024)[t];
    if (t < 8) bs[t] = b[rg * 8 + t];
    __syncthreads();
    const int v = vb * 1024 + t * 4;
    f32x4 acc[8] = {};
    #pragma unroll 8
    for (int j = 0; j < 128; ++j) {
        f32x4 xv = *reinterpret_cast<const f32x4*>(x + (size_t)j * V + v);
        #pragma unroll
        for (int q = 0; q < 8; ++q) acc[q] += Ws[q * 128 + j] * xv;
    }
    #pragma unroll
    for (int q = 0; q < 8; ++q) {
        u16x4 u;
        #pragma unroll
        for (int j = 0; j < 4; ++j) u[j] = f2bf(acc[q][j] + bs[q]);
        *reinterpret_cast<u16x4*>(zb + (size_t)(rg * 8 + q) * V + v) = u;
    }
}

// ---- kernel 2: partial[p,kh] = z[p] @ A[p][k-half]  (bf16 MFMA) --------
// grid (128 n-tiles, 3 p, 2 k-halves), 256 thr = 4 waves.
// Tile 128M x 32N, K-slab 2048, BK=64, 2-phase prefetch + dbuf LDS.
__global__ __launch_bounds__(256) void k_gemm(const unsigned short* __restrict__ zb,
                                              const float* __restrict__ A,
                                              float* __restrict__ partial) {
    __shared__ unsigned short Bt[2][32][72];   // [buf][n][k] bf16, pitch 72
    const int nt = blockIdx.x;
    const int p  = blockIdx.y;
    const int kh = blockIdx.z;
    const int n0 = nt * 32;
    const int kbase = kh * 2048, kend = kbase + 2048;
    const int t    = threadIdx.x;
    const int wid  = t >> 6;
    const int lane = t & 63;
    const int lrow = lane & 15;
    const int g    = lane >> 4;

    const float* Ap = A + (size_t)p * V * V;
    const unsigned short* Zw = zb + ((size_t)p * 128 + wid * 32) * V + (size_t)lrow * V + g * 8;

    const int kk = t >> 2;      // staging row 0..63
    const int c4 = t & 3;       // staging col-quad

    f32x4 acc00 = {}, acc01 = {}, acc10 = {}, acc11 = {};
    f32x4 aA0, aA1, aB0, aB1;
    bf16x8 zA0, zA1, zA2, zA3, zB0, zB1, zB2, zB3;

#define LOADA(d0, d1, K) { const float* s_ = Ap + (size_t)((K) + kk) * V + n0 + c4 * 4; \
        d0 = *reinterpret_cast<const f32x4*>(s_); \
        d1 = *reinterpret_cast<const f32x4*>(s_ + 16); }

#define LOADZ(z0_, z1_, z2_, z3_, K) { const unsigned short* zr_ = Zw + (K); \
        z0_ = *reinterpret_cast<const bf16x8*>(zr_); \
        z1_ = *reinterpret_cast<const bf16x8*>(zr_ + (size_t)16 * V); \
        z2_ = *reinterpret_cast<const bf16x8*>(zr_ + 32); \
        z3_ = *reinterpret_cast<const bf16x8*>(zr_ + (size_t)16 * V + 32); }

#define WRITELDS(B, a0, a1) { \
        Bt[B][c4 * 4 + 0][kk] = f2bf(a0[0]); Bt[B][c4 * 4 + 1][kk] = f2bf(a0[1]); \
        Bt[B][c4 * 4 + 2][kk] = f2bf(a0[2]); Bt[B][c4 * 4 + 3][kk] = f2bf(a0[3]); \
        Bt[B][16 + c4 * 4 + 0][kk] = f2bf(a1[0]); Bt[B][16 + c4 * 4 + 1][kk] = f2bf(a1[1]); \
        Bt[B][16 + c4 * 4 + 2][kk] = f2bf(a1[2]); Bt[B][16 + c4 * 4 + 3][kk] = f2bf(a1[3]); }

#define MFMA_PHASE(B, zz0, zz1, zz2, zz3) { \
        bf16x8 b0l = *reinterpret_cast<const bf16x8*>(&Bt[B][lrow][g * 8]); \
        bf16x8 b1l = *reinterpret_cast<const bf16x8*>(&Bt[B][16 + lrow][g * 8]); \
        bf16x8 b0h = *reinterpret_cast<const bf16x8*>(&Bt[B][lrow][32 + g * 8]); \
        bf16x8 b1h = *reinterpret_cast<const bf16x8*>(&Bt[B][16 + lrow][32 + g * 8]); \
        acc00 = __builtin_amdgcn_mfma_f32_16x16x32_bf16(zz0, b0l, acc00, 0, 0, 0); \
        acc01 = __builtin_amdgcn_mfma_f32_16x16x32_bf16(zz0, b1l, acc01, 0, 0, 0); \
        acc10 = __builtin_amdgcn_mfma_f32_16x16x32_bf16(zz1, b0l, acc10, 0, 0, 0); \
        acc11 = __builtin_amdgcn_mfma_f32_16x16x32_bf16(zz1, b1l, acc11, 0, 0, 0); \
        acc00 = __builtin_amdgcn_mfma_f32_16x16x32_bf16(zz2, b0h, acc00, 0, 0, 0); \
        acc01 = __builtin_amdgcn_mfma_f32_16x16x32_bf16(zz2, b1h, acc01, 0, 0, 0); \
        acc10 = __builtin_amdgcn_mfma_f32_16x16x32_bf16(zz3, b0h, acc10, 0, 0, 0); \
        acc11 = __builtin_amdgcn_mfma_f32_16x16x32_bf16(zz3, b1h, acc11, 0, 0, 0); }

    // prologue: 2 A-tiles + 1 z-phase in flight
    LOADA(aA0, aA1, kbase);
    LOADA(aB0, aB1, kbase + 64);
    LOADZ(zA0, zA1, zA2, zA3, kbase);

    for (int k0 = kbase; k0 < kend; k0 += 128) {
        const int kA = (k0 + 128 < kend) ? k0 + 128 : kend - 64;   // clamp: redundant re-read, never used wrong
        const int kB = (k0 + 192 < kend) ? k0 + 192 : kend - 64;
        const int kZ = (k0 + 128 < kend) ? k0 + 128 : kbase;

        __syncthreads();                 // readers of buf0 done
        WRITELDS(0, aA0, aA1);           // waits vmcnt for aA only
        __syncthreads();                 // buf0 visible
        LOADA(aA0, aA1, kA);             // issue tile t+2 — in flight across MFMA
        LOADZ(zB0, zB1, zB2, zB3, k0 + 64);
        MFMA_PHASE(0, zA0, zA1, zA2, zA3);

        __syncthreads();                 // readers of buf1 done
        WRITELDS(1, aB0, aB1);
        __syncthreads();                 // buf1 visible
        LOADA(aB0, aB1, kB);
        LOADZ(zA0, zA1, zA2, zA3, kZ);
        MFMA_PHASE(1, zB0, zB1, zB2, zB3);
    }

    // C/D layout: col = lane&15, row = (lane>>4)*4 + reg   [verified m89/m91]
    float* Pp = partial + (size_t)(p * 2 + kh) * 128 * V;
    #pragma unroll
    for (int r = 0; r < 4; ++r) {
        const int m0 = wid * 32 + g * 4 + r;
        Pp[(size_t)m0 * V + n0 + lrow]             = acc00[r];
        Pp[(size_t)m0 * V + n0 + 16 + lrow]        = acc01[r];
        Pp[(size_t)(m0 + 16) * V + n0 + lrow]      = acc10[r];
        Pp[(size_t)(m0 + 16) * V + n0 + 16 + lrow] = acc11[r];
    }
#undef LOADA
#undef LOADZ
#undef WRITELDS
#undef MFMA_PHASE
}

// ---- kernel 3: out = relu(sum(partials) + sum(fifo[:16] over i,p) + x) -
__global__ __launch_bounds__(256) void k_epi(const float* __restrict__ x,
                                             const float* __restrict__ fifo,
                                             const float* __restrict__ partial,
                                             float* __restrict__ out) {
    const size_t off  = ((size_t)blockIdx.x * 256 + threadIdx.x) * 4;
    const size_t slab = (size_t)128 * V;
    f32x4 s0 = *reinterpret_cast<const f32x4*>(x + off);
    f32x4 s1 = {}, s2 = {}, s3 = {};
    #pragma unroll
    for (int q = 0; q < 6; ++q) {
        f32x4 pv = *reinterpret_cast<const f32x4*>(partial + (size_t)q * slab + off);
        if (q & 1) s1 += pv; else s2 += pv;
    }
    #pragma unroll
    for (int s = 0; s < 48; ++s) {   // fifo[:16] x 3p = first 48 slabs
        f32x4 fv = *reinterpret_cast<const f32x4*>(fifo + (size_t)s * slab + off);
        switch (s & 3) {
            case 0: s0 += fv; break;
            case 1: s1 += fv; break;
            case 2: s2 += fv; break;
            default: s3 += fv; break;
        }
    }
    f32x4 sum = (s0 + s1) + (s2 + s3);
    f32x4 o;
    #pragma unroll
    for (int j = 0; j < 4; ++j) o[j] = fmaxf(sum[j], 0.0f);
    *reinterpret_cast<f32x4*>(out + off) = o;
}

extern "C" void kernel_launch(void* const* d_in, const int* in_sizes, int n_in,
                              void* d_out, int out_size, void* d_ws, size_t ws_size,
                              hipStream_t stream) {
    const float* x    = (const float*)d_in[0];   // (1,128,4096,1)
    const float* A    = (const float*)d_in[1];   // (3,4096,4096)
    const float* fifo = (const float*)d_in[2];   // (17,3,128,4096)
    const float* W    = (const float*)d_in[3];   // (384,128)
    const float* b    = (const float*)d_in[4];   // (384,)
    float* out = (float*)d_out;                  // (1,128,4096) f32

    unsigned short* zb = (unsigned short*)d_ws;                       // 3.0 MB bf16
    float* partial = (float*)((char*)d_ws + (size_t)384 * V * 2);     // 12 MB f32 (6 slabs)

    k_z   <<<dim3(48, 4),     256, 0, stream>>>(x, W, b, zb);
    k_gemm<<<dim3(128, 3, 2), 256, 0, stream>>>(zb, A, partial);
    k_epi <<<dim3(512),       256, 0, stream>>>(x, fifo, partial, out);
}